// Round 12
// baseline (533.823 us; speedup 1.0000x reference)
//
#include <hip/hip_runtime.h>
#include <stdint.h>

typedef short s8v __attribute__((ext_vector_type(8)));
typedef float f4v __attribute__((ext_vector_type(4)));
typedef unsigned short u16;

#define MFMA16(a, b, c) __builtin_amdgcn_mfma_f32_16x16x32_bf16(a, b, c, 0, 0, 0)
#define SCALE 0.1889822365046136f

__device__ __forceinline__ u16 f2bf(float f) {
  union { float f; uint32_t u; } v;
  v.f = f;
  uint32_t u = v.u;
  u += 0x7fffu + ((u >> 16) & 1u);   // RNE
  return (u16)(u >> 16);
}

__device__ __forceinline__ void gld_lds16(const void* g, void* l) {
  __builtin_amdgcn_global_load_lds(
      (const __attribute__((address_space(1))) void*)g,
      (__attribute__((address_space(3))) void*)l, 16, 0, 0);
}

// ---------------------------------------------------------------------------
// prep: x f32 -> bf16 streaming cast; pack W^T for QKV in LANE-ORDER FRAG
// BLOCKS W2[(wtile*7+kt)][lane][8] (wtile = n/16 of the 768-row padded W^T,
// kt = k/32; lane (c16,g) holds n = wtile*16+c16, k = kt*32+g*8..+7). Each
// 1KB block is read by one wave as a single coalesced 16B/lane load — no LDS
// needed for W in the fused kernel. Values = f2bf(same sources) as before.
// Wout packed as [256][224] rows (gemm2 unchanged).
// ---------------------------------------------------------------------------
__global__ void prep_kernel(const float4* __restrict__ x4,
                            const float* __restrict__ Wq,
                            const float* __restrict__ Wkv,
                            const float* __restrict__ Wout,
                            u16* __restrict__ xb,
                            u16* __restrict__ w2,
                            u16* __restrict__ woutt) {
  const int gsz = gridDim.x * blockDim.x;
  const int gt = blockIdx.x * blockDim.x + threadIdx.x;
  for (int i = gt; i < 7340032; i += gsz) {   // 29360128/4
    float4 v = x4[i];
    ushort4 o;
    o.x = f2bf(v.x); o.y = f2bf(v.y); o.z = f2bf(v.z); o.w = f2bf(v.w);
    ((ushort4*)xb)[i] = o;
  }
  for (int i = gt; i < 172032; i += gsz) {    // 48 wtiles * 7 kt * 64 * 8
    const int e = i & 7;
    const int l = (i >> 3) & 63;
    const int wtkt = i >> 9;                  // 0..335
    const int wt = wtkt / 7;                  // magic-mul
    const int kt = wtkt - wt * 7;
    const int n = wt * 16 + (l & 15);
    const int kk = kt * 32 + (l >> 4) * 8 + e;
    float v = 0.f;
    if (n < 224) v = Wq[kk * 224 + n];
    else if (n < 672) v = Wkv[kk * 448 + (n - 224)];
    w2[i] = f2bf(v);
  }
  for (int i = gt; i < 256 * 224; i += gsz) {
    const int n = i / 224, k = i - n * 224;
    const float v = (n < 224) ? Wout[k * 224 + n] : 0.f;
    woutt[i] = f2bf(v);
  }
}

// ---------------------------------------------------------------------------
// gemm_af (output GEMM only): C = A[M][224] * Bt^T. Unchanged.
// ---------------------------------------------------------------------------
template <int OUT_F32, int NTILES>
__global__ __launch_bounds__(256) void gemm_af(const u16* __restrict__ Ap,
                                               const u16* __restrict__ Bt,
                                               void* __restrict__ Cp,
                                               const float* __restrict__ bias,
                                               int Nvalid, int ldc) {
  extern __shared__ u16 smem[];
  u16* As  = smem;            // [128][224] = 57344 B
  u16* Bs0 = smem + 28672;
  u16* Bs1 = smem + 32768;
  const int tid = threadIdx.x;
  const int wave = tid >> 6, lane = tid & 63;
  const int c16 = lane & 15, g = lane >> 4;
  const int m0 = blockIdx.x * 128;
  const int wm = wave & 1, wn = wave >> 1;

  const int fbw = wave * 1024 + lane * 16;
  const int brow0 = fbw >> 6, bcol0 = (fbw & 63) >> 1;

#define STAGE_B(ntile, ktile, bufp)                                            \
  do {                                                                         \
    char* bb = (char*)((bufp) ? Bs1 : Bs0) + wave * 1024;                      \
    const u16* src =                                                           \
        Bt + (size_t)((ntile) * 128 + brow0) * 224 + (ktile) * 32 + bcol0;     \
    gld_lds16(src, bb);                                                        \
    gld_lds16(src + (size_t)64 * 224, bb + 4096);                              \
  } while (0)

  STAGE_B(0, 0, 0);
  if (NTILES * 7 > 1) STAGE_B(0, 1, 1);

  for (int rnd = 0; rnd < 14; ++rnd) {
    const int fb = rnd * 4096 + fbw;
    const int row = fb / 448;
    const int off = fb - row * 448;
    gld_lds16(Ap + (size_t)(m0 + row) * 224 + (off >> 1),
              (char*)As + rnd * 4096 + wave * 1024);
  }
  __syncthreads();

  for (int nt = 0; nt < NTILES; ++nt) {
    f4v acc[4][4] = {};
    for (int kt = 0; kt < 7; ++kt) {
      const int t = nt * 7 + kt;
      const u16* Bs = (t & 1) ? Bs1 : Bs0;
      s8v af[4], bf[4];
      for (int tt = 0; tt < 4; ++tt)
        af[tt] = *(const s8v*)&As[(wm * 64 + tt * 16 + c16) * 224 + kt * 32 + g * 8];
      for (int tt = 0; tt < 4; ++tt)
        bf[tt] = *(const s8v*)&Bs[(wn * 64 + tt * 16 + c16) * 32 + g * 8];
      for (int i = 0; i < 4; ++i)
        for (int j = 0; j < 4; ++j)
          acc[i][j] = MFMA16(af[i], bf[j], acc[i][j]);
      __syncthreads();
      const int ns = t + 2;
      if (ns < NTILES * 7) {
        const int nnt = ns / 7;
        STAGE_B(nnt, ns - nnt * 7, t & 1);
      }
    }
    const int n0 = nt * 128;
    for (int i = 0; i < 4; ++i) {
      const int rowb = m0 + wm * 64 + i * 16 + g * 4;
      for (int j = 0; j < 4; ++j) {
        const int col = n0 + wn * 64 + j * 16 + c16;
        if (col < Nvalid) {
          if (OUT_F32) {
            const float bz = bias[col];
            for (int r = 0; r < 4; ++r)
              ((float*)Cp)[(size_t)(rowb + r) * ldc + col] = acc[i][j][r] + bz;
          } else {
            for (int r = 0; r < 4; ++r)
              ((u16*)Cp)[(size_t)(rowb + r) * ldc + col] = f2bf(acc[i][j][r]);
          }
        }
      }
    }
  }
#undef STAGE_B
}

// ---------------------------------------------------------------------------
// FUSED qkv-GEMM + attention, R12: W never touches LDS.
// Each (tile,kt) B-fragment is consumed by exactly ONE wave, so W is loaded
// direct global->reg from the lane-order-packed W2 (one coalesced 16B/lane
// load per fragment; L2-resident). Next-kt fragments are software-prefetched
// (wf/wfn double-buffer, fully unrolled) under the current kt's MFMAs — the
// W pipeline is decoupled from __syncthreads, which now gates only the tiny
// A subtile ([64][32] gld_lds dbuf, 1 op/thread/kt).
// Phase 2: byte-identical R11.
// LDS (u16): phase1 As0@0(2048) As1@2048 -> 4096. phase2: qs@0[256][32]
//   ks@8192[256][32] | local pm@0[4][64][72](18432, alias) vtL@18432
//   [4][28][72](8064) | global vtG@16384(2056-stride, 8224) p2@24608(2048).
// Peak 26656 u16 = 53312 B -> 3 blocks/CU.
// ---------------------------------------------------------------------------
__global__ __launch_bounds__(256, 3) void attn_fused(
    const u16* __restrict__ xb, const u16* __restrict__ W2,
    const float* __restrict__ pos1, const float* __restrict__ pos2,
    u16* __restrict__ attn) {
  extern __shared__ u16 sm[];
  u16* As0 = sm;            // [64][32] = 2048 u16
  u16* As1 = sm + 2048;
  const int blk0 = blockIdx.x;
  const int local = (blk0 < 2048) ? 1 : 0;
  const int blk = local ? blk0 : blk0 - 2048;
  const int tid = threadIdx.x;
  const int wave = tid >> 6, lane = tid & 63;
  const int c16 = lane & 15, g = lane >> 4;
  const int b = blk >> 4, sub = blk & 15;

  int base_s = 0, ig = 0;
  if (local) {
    base_s = (b * 32 + (sub >> 2) * 8) * 32 + (sub & 3) * 8;
  } else {
    ig = sub;
  }

  // per-thread A staging address: row = tid>>2 (4 x 16B chunks per 64B row)
  int s_a;
  {
    const int arow = tid >> 2;
    if (local) {
      s_a = base_s + (arow >> 3) * 32 + (arow & 7);
    } else {
      const int w2i = arow >> 4, j = arow & 15;
      const int ii = ig * 4 + w2i;
      const int y = ii >> 3, x = ii & 7;
      s_a = (b * 32 + (j >> 2) * 8 + y) * 32 + (j & 3) * 8 + x;
    }
  }
  const int a_off = (tid & 3) * 8;

#define STAGE_A(ktile, buf)                                                   \
  gld_lds16(xb + (size_t)s_a * 224 + (ktile) * 32 + a_off,                    \
            (char*)(buf) + tid * 16)

  STAGE_A(0, As0);
  STAGE_A(1, As1);

  // per-wave W fragment pointers: branch-rel tile t -> W-tile t+7*seg+(7 if global)
  const u16* wp[6];
#pragma unroll
  for (int j = 0; j < 6; ++j) {
    const int t = j * 4 + wave;
    const int seg = (t >= 14) ? 2 : ((t >= 7) ? 1 : 0);
    const int wtile = t + 7 * seg + (local ? 0 : 7);
    wp[j] = W2 + ((size_t)(wtile * 7) << 9) + lane * 8;   // *7*512 u16 blocks? no:
  }
  // NOTE: block stride is 1024 u16 per (wtile,kt); base = wtile*7*1024? fix below.

  // (recompute with correct stride — 1KB block = 512 u16)
  // W2 index: ((wtile*7 + kt)*64 + lane)*8 u16 = (wtile*7+kt)*512 + lane*8
#pragma unroll
  for (int j = 0; j < 6; ++j) {
    const int t = j * 4 + wave;
    const int seg = (t >= 14) ? 2 : ((t >= 7) ? 1 : 0);
    const int wtile = t + 7 * seg + (local ? 0 : 7);
    wp[j] = W2 + (size_t)(wtile * 7) * 512 + lane * 8;
  }

  // preload kt=0 fragments (fly under the A gld_lds drain)
  s8v wf[6];
#pragma unroll
  for (int j = 0; j < 6; ++j)
    if (j * 4 + wave < 21) wf[j] = *(const s8v*)(wp[j]);

  __syncthreads();   // drains As0/As1 staging

  // ---- mini-GEMM: acc[tile j][strip], tile = j*4+wave (<21), K = 7 steps
  f4v acc[6][4] = {};
#pragma unroll
  for (int kt = 0; kt < 7; ++kt) {
    s8v wfn[6];
    if (kt < 6) {
#pragma unroll
      for (int j = 0; j < 6; ++j)
        if (j * 4 + wave < 21)
          wfn[j] = *(const s8v*)(wp[j] + (kt + 1) * 512);   // prefetch under MFMA
    }
    const u16* Asb = (kt & 1) ? As1 : As0;
    s8v af[4];
#pragma unroll
    for (int st = 0; st < 4; ++st)
      af[st] = *(const s8v*)&Asb[(st * 16 + c16) * 32 + g * 8];
#pragma unroll
    for (int j = 0; j < 6; ++j) {
      if (j * 4 + wave < 21) {
#pragma unroll
        for (int st = 0; st < 4; ++st)
          acc[j][st] = MFMA16(af[st], wf[j], acc[j][st]);
      }
    }
    __syncthreads();       // all waves done reading As[kt&1]
    if (kt + 2 < 7) STAGE_A(kt + 2, (kt & 1) ? As1 : As0);
    if (kt < 6) {
#pragma unroll
      for (int j = 0; j < 6; ++j) wf[j] = wfn[j];
    }
  }

  // ---- phase-2 LDS views (As dead after the final barrier)
  u16* qs  = sm;            // [256][32] = 8192 u16
  u16* ks  = sm + 8192;     // [256][32] = 8192 u16
  u16* pm  = sm;            // local P, [4][64][72] = 18432 u16 (alias qs+ks+gap)
  u16* vtL = sm + 18432;    // local [4][28][72] = 8064 u16
  u16* vtG = sm + 16384;    // global, [4] w-stride 2056 = 8224 u16
  u16* p2  = sm + 24608;    // global P, [4][16][32] = 2048 u16

  // ---- C -> LDS in attn layouts; values bit-identical to old qkv
#pragma unroll
  for (int j = 0; j < 6; ++j) {
    const int tile = j * 4 + wave;
    if (tile < 21) {
      const int seg = (tile >= 14) ? 2 : ((tile >= 7) ? 1 : 0);
      const int nn = tile * 16 + c16 - seg * 112;   // 0..111
      const int h = ((nn >= 28) ? 1 : 0) + ((nn >= 56) ? 1 : 0) + ((nn >= 84) ? 1 : 0);
      const int d = nn - h * 28;
#pragma unroll
      for (int st = 0; st < 4; ++st) {
        if (seg == 2) {      // V: 4 consecutive tokens -> one 8B store
          ushort4 o;
          o.x = f2bf(acc[j][st][0]); o.y = f2bf(acc[j][st][1]);
          o.z = f2bf(acc[j][st][2]); o.w = f2bf(acc[j][st][3]);
          if (local)
            *(ushort4*)&vtL[(h * 28 + d) * 72 + st * 16 + g * 4] = o;
          else
            *(ushort4*)&vtG[st * 2056 + (h * 32 + d) * 16 + g * 4] = o;
        } else {
          u16* dst = seg ? ks : qs;
#pragma unroll
          for (int r = 0; r < 4; ++r) {
            const u16 v = f2bf(acc[j][st][r]);
            if (local)
              dst[(h * 64 + st * 16 + g * 4 + r) * 32 + d] = v;
            else
              dst[((st * 4 + h) * 16 + g * 4 + r) * 32 + d] = v;
          }
        }
      }
    }
  }
  // zero K-pads d=28..31 of qs/ks (all 256 rows); global: vtG rows 28..31
  {
    const ushort4 z = {0, 0, 0, 0};
    *(ushort4*)(qs + tid * 32 + 28) = z;
    *(ushort4*)(ks + tid * 32 + 28) = z;
    if (!local) {
      const int w2i = tid >> 6, hq = (tid >> 4) & 3;
      const int dd = 28 + ((tid >> 2) & 3), j4 = tid & 3;
      *(ushort4*)(vtG + w2i * 2056 + (hq * 32 + dd) * 16 + j4 * 4) = z;
    }
  }
  __syncthreads();

  const f4v fz = {0.f, 0.f, 0.f, 0.f};
  if (local) {
    // ================= local attn body (R11) =================
    const int h = wave;
    s8v af2[4], bf2[4];
    for (int t = 0; t < 4; ++t)
      af2[t] = *(const s8v*)&qs[(h * 64 + t * 16 + c16) * 32 + g * 8];
    for (int t = 0; t < 4; ++t)
      bf2[t] = *(const s8v*)&ks[(h * 64 + t * 16 + c16) * 32 + g * 8];
    f4v sc[4][4];
    for (int i = 0; i < 4; ++i)
      for (int j = 0; j < 4; ++j)
        sc[i][j] = MFMA16(af2[i], bf2[j], fz);
    float lrow[4][4];
    const float* ph = pos1 + h * 4096;
    for (int i = 0; i < 4; ++i) {
      for (int r = 0; r < 4; ++r) {
        const int irow = i * 16 + g * 4 + r;
        float mx = -1e30f;
        for (int j = 0; j < 4; ++j) {
          const float v = sc[i][j][r] * SCALE + ph[irow * 64 + j * 16 + c16];
          sc[i][j][r] = v;
          mx = fmaxf(mx, v);
        }
        for (int dd = 1; dd < 16; dd <<= 1) mx = fmaxf(mx, __shfl_xor(mx, dd, 64));
        float sum = 0.f;
        for (int j = 0; j < 4; ++j) {
          const float e = __expf(sc[i][j][r] - mx);
          sc[i][j][r] = e;
          sum += e;
        }
        for (int dd = 1; dd < 16; dd <<= 1) sum += __shfl_xor(sum, dd, 64);
        lrow[i][r] = sum;
      }
    }
    __syncthreads();   // qs/ks frag reads done before pm (aliased) written
    for (int i = 0; i < 4; ++i)
      for (int r = 0; r < 4; ++r) {
        const int irow = i * 16 + g * 4 + r;
        for (int j = 0; j < 4; ++j)
          pm[(h * 64 + irow) * 72 + j * 16 + c16] = f2bf(sc[i][j][r]);
      }
    f4v o[4][2] = {};
    for (int kk = 0; kk < 2; ++kk) {
      s8v ap[4], bv[2];
      for (int t = 0; t < 4; ++t)
        ap[t] = *(const s8v*)&pm[(h * 64 + t * 16 + c16) * 72 + kk * 32 + g * 8];
      for (int t = 0; t < 2; ++t)
        bv[t] = *(const s8v*)&vtL[(h * 28 + t * 16 + c16) * 72 + kk * 32 + g * 8];
      for (int i = 0; i < 4; ++i)
        for (int j = 0; j < 2; ++j)
          o[i][j] = MFMA16(ap[i], bv[j], o[i][j]);
    }
    for (int i = 0; i < 4; ++i)
      for (int r = 0; r < 4; ++r) {
        const int irow = i * 16 + g * 4 + r;
        const int s = base_s + (irow >> 3) * 32 + (irow & 7);
        const float inv = 1.f / lrow[i][r];
        for (int j = 0; j < 2; ++j) {
          const int d = j * 16 + c16;
          if (d < 28)
            attn[(size_t)s * 224 + h * 28 + d] = f2bf(o[i][j][r] * inv);
        }
      }
  } else {
    // ================= global attn body (R11) =================
    const int w = wave;
    const int i = ig * 4 + w;
    const int y = i >> 3, x = i & 7;
    const int w4 = w * 4;
    for (int h = 0; h < 4; ++h) {
      const s8v aq = *(const s8v*)&qs[((w4 + h) * 16 + c16) * 32 + g * 8];
      const s8v bk = *(const s8v*)&ks[((w4 + h) * 16 + c16) * 32 + g * 8];
      const f4v s = MFMA16(aq, bk, fz);
      const float* ph = pos2 + h * 256;
      float l[4];
      for (int r = 0; r < 4; ++r) {
        const float v = s[r] * SCALE + ph[(g * 4 + r) * 16 + c16];
        float mx = v;
        for (int dd = 1; dd < 16; dd <<= 1) mx = fmaxf(mx, __shfl_xor(mx, dd, 64));
        const float e = __expf(v - mx);
        float sum = e;
        for (int dd = 1; dd < 16; dd <<= 1) sum += __shfl_xor(sum, dd, 64);
        l[r] = sum;
        p2[(w * 16 + g * 4 + r) * 32 + c16] = f2bf(e);
        p2[(w * 16 + g * 4 + r) * 32 + c16 + 16] = 0;   // K pad
      }
      const s8v ap = *(const s8v*)&p2[(w * 16 + c16) * 32 + g * 8];  // same-wave RAW
      f4v o[2];
      for (int nt = 0; nt < 2; ++nt) {
        s8v bv = {0, 0, 0, 0, 0, 0, 0, 0};
        if (g < 2)
          bv = *(const s8v*)&vtG[w * 2056 + (h * 32 + nt * 16 + c16) * 16 + g * 8];
        o[nt] = MFMA16(ap, bv, fz);
      }
      for (int nt = 0; nt < 2; ++nt)
        for (int r = 0; r < 4; ++r) {
          const int d = nt * 16 + c16;
          if (d < 28) {
            const int wi = g * 4 + r;
            const int sw = (b * 32 + (wi >> 2) * 8 + y) * 32 + (wi & 3) * 8 + x;
            attn[(size_t)sw * 224 + 112 + h * 28 + d] = f2bf(o[nt][r] / l[r]);
          }
        }
    }
  }
#undef STAGE_A
}

// ---------------------------------------------------------------------------
// ws layout (bytes):
//   xb    @ 0          : 131072*224*2 = 58,720,256
//   attn  @ 58720256   : 131072*224*2 = 58,720,256
//   w2    @ 117440512  : 48*7*512*2   =    344,064   (lane-order W frags)
//   woutt @ 117784576  : 256*224*2    =    114,688
// ---------------------------------------------------------------------------
extern "C" void kernel_launch(void* const* d_in, const int* in_sizes, int n_in,
                              void* d_out, int out_size, void* d_ws, size_t ws_size,
                              hipStream_t stream) {
  const float* x    = (const float*)d_in[0];
  const float* Wq   = (const float*)d_in[1];
  const float* Wkv  = (const float*)d_in[2];
  const float* Wout = (const float*)d_in[3];
  const float* bout = (const float*)d_in[4];
  const float* pos1 = (const float*)d_in[5];
  const float* pos2 = (const float*)d_in[6];
  char* ws = (char*)d_ws;
  u16* xb    = (u16*)ws;
  u16* attn  = (u16*)(ws + 58720256);
  u16* w2    = (u16*)(ws + 117440512);
  u16* woutt = (u16*)(ws + 117784576);

  prep_kernel<<<dim3(1024), 256, 0, stream>>>(
      (const float4*)x, Wq, Wkv, Wout, xb, w2, woutt);

  // fused qkv-GEMM + attention; W direct-to-reg, only A staged (53312B LDS)
  attn_fused<<<dim3(4096), 256, 53312, stream>>>(xb, w2, pos1, pos2, attn);

  // out = attn @ Wout + bout (f32 out, N=224 -> 2 n-tiles)
  gemm_af<1, 2><<<dim3(1024), 256, 73728, stream>>>(attn, woutt, d_out, bout, 224, 224);
}

// Round 13
// 367.300 us; speedup vs baseline: 1.4534x; 1.4534x over previous
//
#include <hip/hip_runtime.h>
#include <stdint.h>

typedef short s8v __attribute__((ext_vector_type(8)));
typedef float f4v __attribute__((ext_vector_type(4)));
typedef unsigned short u16;

#define MFMA16(a, b, c) __builtin_amdgcn_mfma_f32_16x16x32_bf16(a, b, c, 0, 0, 0)
#define SCALE 0.1889822365046136f

__device__ __forceinline__ u16 f2bf(float f) {
  union { float f; uint32_t u; } v;
  v.f = f;
  uint32_t u = v.u;
  u += 0x7fffu + ((u >> 16) & 1u);   // RNE
  return (u16)(u >> 16);
}

__device__ __forceinline__ void gld_lds16(const void* g, void* l) {
  __builtin_amdgcn_global_load_lds(
      (const __attribute__((address_space(1))) void*)g,
      (__attribute__((address_space(3))) void*)l, 16, 0, 0);
}

// ---------------------------------------------------------------------------
// prep: x f32 -> bf16 streaming cast; W^T for QKV packed in LANE-ORDER FRAG
// BLOCKS w2[(wtile*7+kt)*512 + lane*8 + e]: lane (c16,g) of one wave reads a
// whole (wtile,kt) B-fragment as a single coalesced 16B load. n = wtile*16 +
// c16 (768 rows, zero-padded past 672), k = kt*32 + g*8 + e. Values =
// f2bf(same sources) as the old row-major pack. Wout rows unchanged (gemm2).
// ---------------------------------------------------------------------------
__global__ void prep_kernel(const float4* __restrict__ x4,
                            const float* __restrict__ Wq,
                            const float* __restrict__ Wkv,
                            const float* __restrict__ Wout,
                            u16* __restrict__ xb,
                            u16* __restrict__ w2,
                            u16* __restrict__ woutt) {
  const int gsz = gridDim.x * blockDim.x;
  const int gt = blockIdx.x * blockDim.x + threadIdx.x;
  for (int i = gt; i < 7340032; i += gsz) {   // 29360128/4
    float4 v = x4[i];
    ushort4 o;
    o.x = f2bf(v.x); o.y = f2bf(v.y); o.z = f2bf(v.z); o.w = f2bf(v.w);
    ((ushort4*)xb)[i] = o;
  }
  for (int i = gt; i < 172032; i += gsz) {    // 48 wtiles * 7 kt * 64 * 8
    const int e = i & 7;
    const int l = (i >> 3) & 63;
    const int wtkt = i >> 9;                  // 0..335
    const int wt = wtkt / 7;                  // magic-mul
    const int kt = wtkt - wt * 7;
    const int n = wt * 16 + (l & 15);
    const int kk = kt * 32 + (l >> 4) * 8 + e;
    float v = 0.f;
    if (n < 224) v = Wq[kk * 224 + n];
    else if (n < 672) v = Wkv[kk * 448 + (n - 224)];
    w2[i] = f2bf(v);
  }
  for (int i = gt; i < 256 * 224; i += gsz) {
    const int n = i / 224, k = i - n * 224;
    const float v = (n < 224) ? Wout[k * 224 + n] : 0.f;
    woutt[i] = f2bf(v);
  }
}

// ---------------------------------------------------------------------------
// gemm_af (output GEMM only): C = A[M][224] * Bt^T. Unchanged.
// ---------------------------------------------------------------------------
template <int OUT_F32, int NTILES>
__global__ __launch_bounds__(256) void gemm_af(const u16* __restrict__ Ap,
                                               const u16* __restrict__ Bt,
                                               void* __restrict__ Cp,
                                               const float* __restrict__ bias,
                                               int Nvalid, int ldc) {
  extern __shared__ u16 smem[];
  u16* As  = smem;            // [128][224] = 57344 B
  u16* Bs0 = smem + 28672;
  u16* Bs1 = smem + 32768;
  const int tid = threadIdx.x;
  const int wave = tid >> 6, lane = tid & 63;
  const int c16 = lane & 15, g = lane >> 4;
  const int m0 = blockIdx.x * 128;
  const int wm = wave & 1, wn = wave >> 1;

  const int fbw = wave * 1024 + lane * 16;
  const int brow0 = fbw >> 6, bcol0 = (fbw & 63) >> 1;

#define STAGE_B(ntile, ktile, bufp)                                            \
  do {                                                                         \
    char* bb = (char*)((bufp) ? Bs1 : Bs0) + wave * 1024;                      \
    const u16* src =                                                           \
        Bt + (size_t)((ntile) * 128 + brow0) * 224 + (ktile) * 32 + bcol0;     \
    gld_lds16(src, bb);                                                        \
    gld_lds16(src + (size_t)64 * 224, bb + 4096);                              \
  } while (0)

  STAGE_B(0, 0, 0);
  if (NTILES * 7 > 1) STAGE_B(0, 1, 1);

  for (int rnd = 0; rnd < 14; ++rnd) {
    const int fb = rnd * 4096 + fbw;
    const int row = fb / 448;
    const int off = fb - row * 448;
    gld_lds16(Ap + (size_t)(m0 + row) * 224 + (off >> 1),
              (char*)As + rnd * 4096 + wave * 1024);
  }
  __syncthreads();

  for (int nt = 0; nt < NTILES; ++nt) {
    f4v acc[4][4] = {};
    for (int kt = 0; kt < 7; ++kt) {
      const int t = nt * 7 + kt;
      const u16* Bs = (t & 1) ? Bs1 : Bs0;
      s8v af[4], bf[4];
      for (int tt = 0; tt < 4; ++tt)
        af[tt] = *(const s8v*)&As[(wm * 64 + tt * 16 + c16) * 224 + kt * 32 + g * 8];
      for (int tt = 0; tt < 4; ++tt)
        bf[tt] = *(const s8v*)&Bs[(wn * 64 + tt * 16 + c16) * 32 + g * 8];
      for (int i = 0; i < 4; ++i)
        for (int j = 0; j < 4; ++j)
          acc[i][j] = MFMA16(af[i], bf[j], acc[i][j]);
      __syncthreads();
      const int ns = t + 2;
      if (ns < NTILES * 7) {
        const int nnt = ns / 7;
        STAGE_B(nnt, ns - nnt * 7, t & 1);
      }
    }
    const int n0 = nt * 128;
    for (int i = 0; i < 4; ++i) {
      const int rowb = m0 + wm * 64 + i * 16 + g * 4;
      for (int j = 0; j < 4; ++j) {
        const int col = n0 + wn * 64 + j * 16 + c16;
        if (col < Nvalid) {
          if (OUT_F32) {
            const float bz = bias[col];
            for (int r = 0; r < 4; ++r)
              ((float*)Cp)[(size_t)(rowb + r) * ldc + col] = acc[i][j][r] + bz;
          } else {
            for (int r = 0; r < 4; ++r)
              ((u16*)Cp)[(size_t)(rowb + r) * ldc + col] = f2bf(acc[i][j][r]);
          }
        }
      }
    }
  }
#undef STAGE_B
}

// ---------------------------------------------------------------------------
// FUSED qkv-GEMM + attention, R13: W direct-to-reg, REGISTER-FRUGAL.
// R12 lesson: wf/wfn prefetch double-buffer (+48 live VGPRs) spilled acc to
// scratch (787MB writes). Here each B-fragment is loaded INLINE one at a time
// (transient bf) from the lane-order W2 pack — one coalesced 16B/lane L2
// load per (tile,kt); the compiler hoists the 6 independent loads ahead of
// the MFMA chain itself. Live set ~140 VGPR < 168 (3 waves/SIMD budget).
// W never touches LDS; the per-kt barrier gates only the A subtile
// ([64][32] gld_lds dbuf, 1 op/thread/kt). Phase 2: byte-identical R11.
// LDS (u16): phase1 As0@0(2048) As1@2048 -> 4096. phase2: qs@0[256][32]
//   ks@8192 | local pm@0(18432, alias) vtL@18432[4][28][72](8064) | global
//   vtG@16384(2056-stride, 8224) p2@24608(2048). Peak 26656 u16 = 53312 B
//   -> 3 blocks/CU.
// ---------------------------------------------------------------------------
__global__ __launch_bounds__(256, 3) void attn_fused(
    const u16* __restrict__ xb, const u16* __restrict__ W2,
    const float* __restrict__ pos1, const float* __restrict__ pos2,
    u16* __restrict__ attn) {
  extern __shared__ u16 sm[];
  u16* As0 = sm;            // [64][32] = 2048 u16
  u16* As1 = sm + 2048;
  const int blk0 = blockIdx.x;
  const int local = (blk0 < 2048) ? 1 : 0;
  const int blk = local ? blk0 : blk0 - 2048;
  const int tid = threadIdx.x;
  const int wave = tid >> 6, lane = tid & 63;
  const int c16 = lane & 15, g = lane >> 4;
  const int b = blk >> 4, sub = blk & 15;

  int base_s = 0, ig = 0;
  if (local) {
    base_s = (b * 32 + (sub >> 2) * 8) * 32 + (sub & 3) * 8;
  } else {
    ig = sub;
  }

  // per-thread A staging address: row = tid>>2 (4 x 16B chunks per 64B row)
  int s_a;
  {
    const int arow = tid >> 2;
    if (local) {
      s_a = base_s + (arow >> 3) * 32 + (arow & 7);
    } else {
      const int w2i = arow >> 4, j = arow & 15;
      const int ii = ig * 4 + w2i;
      const int y = ii >> 3, x = ii & 7;
      s_a = (b * 32 + (j >> 2) * 8 + y) * 32 + (j & 3) * 8 + x;
    }
  }
  const int a_off = (tid & 3) * 8;

#define STAGE_A(ktile, buf)                                                   \
  gld_lds16(xb + (size_t)s_a * 224 + (ktile) * 32 + a_off,                    \
            (char*)(buf) + tid * 16)

  STAGE_A(0, As0);
  STAGE_A(1, As1);

  // per-wave W fragment base offsets (u16 units), static-indexed thereafter.
  // branch tile t = j*4+wave -> W wtile = t + 7*seg (+7 if global branch);
  // W2 index = (wtile*7 + kt)*512 + lane*8.
  int off[6];
#pragma unroll
  for (int j = 0; j < 6; ++j) {
    const int t = j * 4 + wave;
    const int seg = (t >= 14) ? 2 : ((t >= 7) ? 1 : 0);
    const int wtile = t + 7 * seg + (local ? 0 : 7);
    off[j] = wtile * 7 * 512 + lane * 8;
  }

  __syncthreads();   // drains As0/As1 staging

  // ---- mini-GEMM: acc[tile j][strip], tile = j*4+wave (<21), K = 7 steps
  f4v acc[6][4] = {};
  for (int kt = 0; kt < 7; ++kt) {
    const u16* Asb = (kt & 1) ? As1 : As0;
    s8v af[4];
#pragma unroll
    for (int st = 0; st < 4; ++st)
      af[st] = *(const s8v*)&Asb[(st * 16 + c16) * 32 + g * 8];
#pragma unroll
    for (int j = 0; j < 6; ++j) {
      if (j * 4 + wave < 21) {
        const s8v bf = *(const s8v*)(W2 + off[j] + kt * 512);  // L2, coalesced
#pragma unroll
        for (int st = 0; st < 4; ++st)
          acc[j][st] = MFMA16(af[st], bf, acc[j][st]);
      }
    }
    __syncthreads();       // all waves done reading As[kt&1]
    if (kt + 2 < 7) STAGE_A(kt + 2, (kt & 1) ? As1 : As0);
  }

  // ---- phase-2 LDS views (As dead after the final barrier)
  u16* qs  = sm;            // [256][32] = 8192 u16
  u16* ks  = sm + 8192;     // [256][32] = 8192 u16
  u16* pm  = sm;            // local P, [4][64][72] = 18432 u16 (alias qs+ks+gap)
  u16* vtL = sm + 18432;    // local [4][28][72] = 8064 u16
  u16* vtG = sm + 16384;    // global, [4] w-stride 2056 = 8224 u16
  u16* p2  = sm + 24608;    // global P, [4][16][32] = 2048 u16

  // ---- C -> LDS in attn layouts; values bit-identical to old qkv
#pragma unroll
  for (int j = 0; j < 6; ++j) {
    const int tile = j * 4 + wave;
    if (tile < 21) {
      const int seg = (tile >= 14) ? 2 : ((tile >= 7) ? 1 : 0);
      const int nn = tile * 16 + c16 - seg * 112;   // 0..111
      const int h = ((nn >= 28) ? 1 : 0) + ((nn >= 56) ? 1 : 0) + ((nn >= 84) ? 1 : 0);
      const int d = nn - h * 28;
#pragma unroll
      for (int st = 0; st < 4; ++st) {
        if (seg == 2) {      // V: 4 consecutive tokens -> one 8B store
          ushort4 o;
          o.x = f2bf(acc[j][st][0]); o.y = f2bf(acc[j][st][1]);
          o.z = f2bf(acc[j][st][2]); o.w = f2bf(acc[j][st][3]);
          if (local)
            *(ushort4*)&vtL[(h * 28 + d) * 72 + st * 16 + g * 4] = o;
          else
            *(ushort4*)&vtG[st * 2056 + (h * 32 + d) * 16 + g * 4] = o;
        } else {
          u16* dst = seg ? ks : qs;
#pragma unroll
          for (int r = 0; r < 4; ++r) {
            const u16 v = f2bf(acc[j][st][r]);
            if (local)
              dst[(h * 64 + st * 16 + g * 4 + r) * 32 + d] = v;
            else
              dst[((st * 4 + h) * 16 + g * 4 + r) * 32 + d] = v;
          }
        }
      }
    }
  }
  // zero K-pads d=28..31 of qs/ks (all 256 rows); global: vtG rows 28..31
  {
    const ushort4 z = {0, 0, 0, 0};
    *(ushort4*)(qs + tid * 32 + 28) = z;
    *(ushort4*)(ks + tid * 32 + 28) = z;
    if (!local) {
      const int w2i = tid >> 6, hq = (tid >> 4) & 3;
      const int dd = 28 + ((tid >> 2) & 3), j4 = tid & 3;
      *(ushort4*)(vtG + w2i * 2056 + (hq * 32 + dd) * 16 + j4 * 4) = z;
    }
  }
  __syncthreads();

  const f4v fz = {0.f, 0.f, 0.f, 0.f};
  if (local) {
    // ================= local attn body (R11) =================
    const int h = wave;
    s8v af2[4], bf2[4];
    for (int t = 0; t < 4; ++t)
      af2[t] = *(const s8v*)&qs[(h * 64 + t * 16 + c16) * 32 + g * 8];
    for (int t = 0; t < 4; ++t)
      bf2[t] = *(const s8v*)&ks[(h * 64 + t * 16 + c16) * 32 + g * 8];
    f4v sc[4][4];
    for (int i = 0; i < 4; ++i)
      for (int j = 0; j < 4; ++j)
        sc[i][j] = MFMA16(af2[i], bf2[j], fz);
    float lrow[4][4];
    const float* ph = pos1 + h * 4096;
    for (int i = 0; i < 4; ++i) {
      for (int r = 0; r < 4; ++r) {
        const int irow = i * 16 + g * 4 + r;
        float mx = -1e30f;
        for (int j = 0; j < 4; ++j) {
          const float v = sc[i][j][r] * SCALE + ph[irow * 64 + j * 16 + c16];
          sc[i][j][r] = v;
          mx = fmaxf(mx, v);
        }
        for (int dd = 1; dd < 16; dd <<= 1) mx = fmaxf(mx, __shfl_xor(mx, dd, 64));
        float sum = 0.f;
        for (int j = 0; j < 4; ++j) {
          const float e = __expf(sc[i][j][r] - mx);
          sc[i][j][r] = e;
          sum += e;
        }
        for (int dd = 1; dd < 16; dd <<= 1) sum += __shfl_xor(sum, dd, 64);
        lrow[i][r] = sum;
      }
    }
    __syncthreads();   // qs/ks frag reads done before pm (aliased) written
    for (int i = 0; i < 4; ++i)
      for (int r = 0; r < 4; ++r) {
        const int irow = i * 16 + g * 4 + r;
        for (int j = 0; j < 4; ++j)
          pm[(h * 64 + irow) * 72 + j * 16 + c16] = f2bf(sc[i][j][r]);
      }
    f4v o[4][2] = {};
    for (int kk = 0; kk < 2; ++kk) {
      s8v ap[4], bv[2];
      for (int t = 0; t < 4; ++t)
        ap[t] = *(const s8v*)&pm[(h * 64 + t * 16 + c16) * 72 + kk * 32 + g * 8];
      for (int t = 0; t < 2; ++t)
        bv[t] = *(const s8v*)&vtL[(h * 28 + t * 16 + c16) * 72 + kk * 32 + g * 8];
      for (int i = 0; i < 4; ++i)
        for (int j = 0; j < 2; ++j)
          o[i][j] = MFMA16(ap[i], bv[j], o[i][j]);
    }
    for (int i = 0; i < 4; ++i)
      for (int r = 0; r < 4; ++r) {
        const int irow = i * 16 + g * 4 + r;
        const int s = base_s + (irow >> 3) * 32 + (irow & 7);
        const float inv = 1.f / lrow[i][r];
        for (int j = 0; j < 2; ++j) {
          const int d = j * 16 + c16;
          if (d < 28)
            attn[(size_t)s * 224 + h * 28 + d] = f2bf(o[i][j][r] * inv);
        }
      }
  } else {
    // ================= global attn body (R11) =================
    const int w = wave;
    const int i = ig * 4 + w;
    const int y = i >> 3, x = i & 7;
    const int w4 = w * 4;
    for (int h = 0; h < 4; ++h) {
      const s8v aq = *(const s8v*)&qs[((w4 + h) * 16 + c16) * 32 + g * 8];
      const s8v bk = *(const s8v*)&ks[((w4 + h) * 16 + c16) * 32 + g * 8];
      const f4v s = MFMA16(aq, bk, fz);
      const float* ph = pos2 + h * 256;
      float l[4];
      for (int r = 0; r < 4; ++r) {
        const float v = s[r] * SCALE + ph[(g * 4 + r) * 16 + c16];
        float mx = v;
        for (int dd = 1; dd < 16; dd <<= 1) mx = fmaxf(mx, __shfl_xor(mx, dd, 64));
        const float e = __expf(v - mx);
        float sum = e;
        for (int dd = 1; dd < 16; dd <<= 1) sum += __shfl_xor(sum, dd, 64);
        l[r] = sum;
        p2[(w * 16 + g * 4 + r) * 32 + c16] = f2bf(e);
        p2[(w * 16 + g * 4 + r) * 32 + c16 + 16] = 0;   // K pad
      }
      const s8v ap = *(const s8v*)&p2[(w * 16 + c16) * 32 + g * 8];  // same-wave RAW
      f4v o[2];
      for (int nt = 0; nt < 2; ++nt) {
        s8v bv = {0, 0, 0, 0, 0, 0, 0, 0};
        if (g < 2)
          bv = *(const s8v*)&vtG[w * 2056 + (h * 32 + nt * 16 + c16) * 16 + g * 8];
        o[nt] = MFMA16(ap, bv, fz);
      }
      for (int nt = 0; nt < 2; ++nt)
        for (int r = 0; r < 4; ++r) {
          const int d = nt * 16 + c16;
          if (d < 28) {
            const int wi = g * 4 + r;
            const int sw = (b * 32 + (wi >> 2) * 8 + y) * 32 + (wi & 3) * 8 + x;
            attn[(size_t)sw * 224 + 112 + h * 28 + d] = f2bf(o[nt][r] / l[r]);
          }
        }
    }
  }
#undef STAGE_A
}

// ---------------------------------------------------------------------------
// ws layout (bytes):
//   xb    @ 0          : 131072*224*2 = 58,720,256
//   attn  @ 58720256   : 131072*224*2 = 58,720,256
//   w2    @ 117440512  : 48*7*512*2   =    344,064   (lane-order W frags)
//   woutt @ 117784576  : 256*224*2    =    114,688
// ---------------------------------------------------------------------------
extern "C" void kernel_launch(void* const* d_in, const int* in_sizes, int n_in,
                              void* d_out, int out_size, void* d_ws, size_t ws_size,
                              hipStream_t stream) {
  const float* x    = (const float*)d_in[0];
  const float* Wq   = (const float*)d_in[1];
  const float* Wkv  = (const float*)d_in[2];
  const float* Wout = (const float*)d_in[3];
  const float* bout = (const float*)d_in[4];
  const float* pos1 = (const float*)d_in[5];
  const float* pos2 = (const float*)d_in[6];
  char* ws = (char*)d_ws;
  u16* xb    = (u16*)ws;
  u16* attn  = (u16*)(ws + 58720256);
  u16* w2    = (u16*)(ws + 117440512);
  u16* woutt = (u16*)(ws + 117784576);

  prep_kernel<<<dim3(1024), 256, 0, stream>>>(
      (const float4*)x, Wq, Wkv, Wout, xb, w2, woutt);

  // fused qkv-GEMM + attention; W direct-to-reg (inline loads), A-only LDS
  attn_fused<<<dim3(4096), 256, 53312, stream>>>(xb, w2, pos1, pos2, attn);

  // out = attn @ Wout + bout (f32 out, N=224 -> 2 n-tiles)
  gemm_af<1, 2><<<dim3(1024), 256, 73728, stream>>>(attn, woutt, d_out, bout, 224, 224);
}

// Round 14
// 345.450 us; speedup vs baseline: 1.5453x; 1.0633x over previous
//
#include <hip/hip_runtime.h>
#include <stdint.h>

typedef short s8v __attribute__((ext_vector_type(8)));
typedef float f4v __attribute__((ext_vector_type(4)));
typedef unsigned short u16;

#define MFMA16(a, b, c) __builtin_amdgcn_mfma_f32_16x16x32_bf16(a, b, c, 0, 0, 0)
#define SCALE 0.1889822365046136f

__device__ __forceinline__ u16 f2bf(float f) {
  union { float f; uint32_t u; } v;
  v.f = f;
  uint32_t u = v.u;
  u += 0x7fffu + ((u >> 16) & 1u);   // RNE
  return (u16)(u >> 16);
}

__device__ __forceinline__ void gld_lds16(const void* g, void* l) {
  __builtin_amdgcn_global_load_lds(
      (const __attribute__((address_space(1))) void*)g,
      (__attribute__((address_space(3))) void*)l, 16, 0, 0);
}

// ---------------------------------------------------------------------------
// prep: x f32 -> bf16 streaming cast; W^T packed PER BRANCH, fragment-
// contiguous: w2[br][kt][tile][512], tile 0..20 (7 q + 7 k + 7 v 16-col
// tiles of that branch's 112-col half), element (l,e): n = seg*224 +
// br*112 + (tile-7*seg)*16 + (l&15), k = kt*32 + (l>>4)*8 + e.
// Staging a kt-slice is then a LINEAR 21KB copy, and a wave reads its
// fragment at [tile*512 + lane*8] (minimum-aliasing b128). Values =
// f2bf(same sources) as before. Wout rows unchanged (gemm2).
// ---------------------------------------------------------------------------
__global__ void prep_kernel(const float4* __restrict__ x4,
                            const float* __restrict__ Wq,
                            const float* __restrict__ Wkv,
                            const float* __restrict__ Wout,
                            u16* __restrict__ xb,
                            u16* __restrict__ w2,
                            u16* __restrict__ woutt) {
  const int gsz = gridDim.x * blockDim.x;
  const int gt = blockIdx.x * blockDim.x + threadIdx.x;
  for (int i = gt; i < 7340032; i += gsz) {   // 29360128/4
    float4 v = x4[i];
    ushort4 o;
    o.x = f2bf(v.x); o.y = f2bf(v.y); o.z = f2bf(v.z); o.w = f2bf(v.w);
    ((ushort4*)xb)[i] = o;
  }
  for (int i = gt; i < 150528; i += gsz) {    // 2 br * 7 kt * 21 tiles * 512
    const int br = (i >= 75264) ? 1 : 0;
    const int rem = i - br * 75264;
    const int blk9 = rem >> 9;                // (kt*21 + tile), 0..146
    const int kt = blk9 / 21;                 // magic-mul
    const int tile = blk9 - kt * 21;
    const int l = (rem >> 3) & 63;
    const int e = rem & 7;
    const int seg = (tile >= 14) ? 2 : ((tile >= 7) ? 1 : 0);
    const int n = seg * 224 + br * 112 + (tile - seg * 7) * 16 + (l & 15);
    const int kk = kt * 32 + ((l >> 4) << 3) + e;
    const float v = (n < 224) ? Wq[kk * 224 + n] : Wkv[kk * 448 + (n - 224)];
    w2[i] = f2bf(v);
  }
  for (int i = gt; i < 256 * 224; i += gsz) {
    const int n = i / 224, k = i - n * 224;
    const float v = (n < 224) ? Wout[k * 224 + n] : 0.f;
    woutt[i] = f2bf(v);
  }
}

// ---------------------------------------------------------------------------
// gemm_af (output GEMM only): C = A[M][224] * Bt^T. Unchanged.
// ---------------------------------------------------------------------------
template <int OUT_F32, int NTILES>
__global__ __launch_bounds__(256) void gemm_af(const u16* __restrict__ Ap,
                                               const u16* __restrict__ Bt,
                                               void* __restrict__ Cp,
                                               const float* __restrict__ bias,
                                               int Nvalid, int ldc) {
  extern __shared__ u16 smem[];
  u16* As  = smem;            // [128][224] = 57344 B
  u16* Bs0 = smem + 28672;
  u16* Bs1 = smem + 32768;
  const int tid = threadIdx.x;
  const int wave = tid >> 6, lane = tid & 63;
  const int c16 = lane & 15, g = lane >> 4;
  const int m0 = blockIdx.x * 128;
  const int wm = wave & 1, wn = wave >> 1;

  const int fbw = wave * 1024 + lane * 16;
  const int brow0 = fbw >> 6, bcol0 = (fbw & 63) >> 1;

#define STAGE_B(ntile, ktile, bufp)                                            \
  do {                                                                         \
    char* bb = (char*)((bufp) ? Bs1 : Bs0) + wave * 1024;                      \
    const u16* src =                                                           \
        Bt + (size_t)((ntile) * 128 + brow0) * 224 + (ktile) * 32 + bcol0;     \
    gld_lds16(src, bb);                                                        \
    gld_lds16(src + (size_t)64 * 224, bb + 4096);                              \
  } while (0)

  STAGE_B(0, 0, 0);
  if (NTILES * 7 > 1) STAGE_B(0, 1, 1);

  for (int rnd = 0; rnd < 14; ++rnd) {
    const int fb = rnd * 4096 + fbw;
    const int row = fb / 448;
    const int off = fb - row * 448;
    gld_lds16(Ap + (size_t)(m0 + row) * 224 + (off >> 1),
              (char*)As + rnd * 4096 + wave * 1024);
  }
  __syncthreads();

  for (int nt = 0; nt < NTILES; ++nt) {
    f4v acc[4][4] = {};
    for (int kt = 0; kt < 7; ++kt) {
      const int t = nt * 7 + kt;
      const u16* Bs = (t & 1) ? Bs1 : Bs0;
      s8v af[4], bf[4];
      for (int tt = 0; tt < 4; ++tt)
        af[tt] = *(const s8v*)&As[(wm * 64 + tt * 16 + c16) * 224 + kt * 32 + g * 8];
      for (int tt = 0; tt < 4; ++tt)
        bf[tt] = *(const s8v*)&Bs[(wn * 64 + tt * 16 + c16) * 32 + g * 8];
      for (int i = 0; i < 4; ++i)
        for (int j = 0; j < 4; ++j)
          acc[i][j] = MFMA16(af[i], bf[j], acc[i][j]);
      __syncthreads();
      const int ns = t + 2;
      if (ns < NTILES * 7) {
        const int nnt = ns / 7;
        STAGE_B(nnt, ns - nnt * 7, t & 1);
      }
    }
    const int n0 = nt * 128;
    for (int i = 0; i < 4; ++i) {
      const int rowb = m0 + wm * 64 + i * 16 + g * 4;
      for (int j = 0; j < 4; ++j) {
        const int col = n0 + wn * 64 + j * 16 + c16;
        if (col < Nvalid) {
          if (OUT_F32) {
            const float bz = bias[col];
            for (int r = 0; r < 4; ++r)
              ((float*)Cp)[(size_t)(rowb + r) * ldc + col] = acc[i][j][r] + bz;
          } else {
            for (int r = 0; r < 4; ++r)
              ((u16*)Cp)[(size_t)(rowb + r) * ldc + col] = f2bf(acc[i][j][r]);
          }
        }
      }
    }
  }
#undef STAGE_B
}

// ---------------------------------------------------------------------------
// FUSED qkv-GEMM + attention, R14: R11's proven pipeline (A+W both via
// gld_lds, distance-2 dbuf, 1 barrier/kt) + the packed-W addressing from
// R12/R13. STAGE_W is now a LINEAR 21KB copy from the branch-ordered w2
// pack (no n-remap math), and the B-fragment read is Bs[tile*512+lane*8]
// (minimum-aliasing b128, no strided-row conflicts). R13 lesson: W loads
// need prefetch distance (inline per-kt L2 loads put latency on the
// critical path); R12 lesson: register prefetch spills — LDS dbuf is the
// right home. Phase 2: byte-identical R11.
// LDS (u16): phase1 As0@0(2048) As1@2048 Bs0@4096(10752) Bs1@14848
//   -> 25600. phase2: qs@0[256][32] ks@8192 | local pm@0(18432, alias)
//   vtL@18432[4][28][72](8064) | global vtG@16384(2056-stride, 8224)
//   p2@24608(2048). Peak 26656 u16 = 53312 B -> 3 blocks/CU.
// ---------------------------------------------------------------------------
__global__ __launch_bounds__(256, 3) void attn_fused(
    const u16* __restrict__ xb, const u16* __restrict__ W2,
    const float* __restrict__ pos1, const float* __restrict__ pos2,
    u16* __restrict__ attn) {
  extern __shared__ u16 sm[];
  u16* As0 = sm;            // [64][32] = 2048 u16
  u16* As1 = sm + 2048;
  u16* Bs0 = sm + 4096;     // [21][512] = 10752 u16
  u16* Bs1 = sm + 14848;    // ends 25600 u16
  const int blk0 = blockIdx.x;
  const int local = (blk0 < 2048) ? 1 : 0;
  const int blk = local ? blk0 : blk0 - 2048;
  const int tid = threadIdx.x;
  const int wave = tid >> 6, lane = tid & 63;
  const int c16 = lane & 15, g = lane >> 4;
  const int b = blk >> 4, sub = blk & 15;

  int base_s = 0, ig = 0;
  if (local) {
    base_s = (b * 32 + (sub >> 2) * 8) * 32 + (sub & 3) * 8;
  } else {
    ig = sub;
  }

  // per-thread A staging address: row = tid>>2 (4 x 16B chunks per 64B row)
  int s_a;
  {
    const int arow = tid >> 2;
    if (local) {
      s_a = base_s + (arow >> 3) * 32 + (arow & 7);
    } else {
      const int w2i = arow >> 4, j = arow & 15;
      const int ii = ig * 4 + w2i;
      const int y = ii >> 3, x = ii & 7;
      s_a = (b * 32 + (j >> 2) * 8 + y) * 32 + (j & 3) * 8 + x;
    }
  }
  const int a_off = (tid & 3) * 8;

#define STAGE_A(ktile, buf)                                                   \
  gld_lds16(xb + (size_t)s_a * 224 + (ktile) * 32 + a_off,                    \
            (char*)(buf) + tid * 16)

  const u16* W2b = W2 + (local ? 0 : 75264);
  // linear copy: kt-slice = 21 tiles x 512 u16 = 1344 x 16B chunks
#define STAGE_W(ktile, buf)                                                   \
  do {                                                                        \
    const u16* wsrc = W2b + (size_t)(ktile) * 10752;                          \
    for (int mm = 0; mm < 6; ++mm) {                                          \
      const int ch = mm * 256 + tid;                                          \
      if (ch < 1344)                                                          \
        gld_lds16(wsrc + ch * 8, (char*)(buf) + ch * 16);                     \
    }                                                                         \
  } while (0)

  STAGE_A(0, As0);
  STAGE_W(0, Bs0);
  STAGE_A(1, As1);
  STAGE_W(1, Bs1);
  __syncthreads();

  // ---- mini-GEMM: acc[tile j][strip], tile = j*4+wave (<21), K = 7 steps
  f4v acc[6][4] = {};
  for (int kt = 0; kt < 7; ++kt) {
    const u16* Bs = (kt & 1) ? Bs1 : Bs0;
    const u16* Asb = (kt & 1) ? As1 : As0;
    s8v af[4];
#pragma unroll
    for (int st = 0; st < 4; ++st)
      af[st] = *(const s8v*)&Asb[(st * 16 + c16) * 32 + g * 8];
#pragma unroll
    for (int j = 0; j < 6; ++j) {
      const int tile = j * 4 + wave;
      if (tile < 21) {
        const s8v bf = *(const s8v*)&Bs[tile * 512 + lane * 8];  // conflict-free
#pragma unroll
        for (int st = 0; st < 4; ++st)
          acc[j][st] = MFMA16(af[st], bf, acc[j][st]);
      }
    }
    __syncthreads();       // stage(kt+1) covered; buffers free; reads done
    if (kt + 2 < 7) {
      STAGE_A(kt + 2, (kt & 1) ? As1 : As0);
      STAGE_W(kt + 2, (kt & 1) ? Bs1 : Bs0);
    }
  }

  // ---- phase-2 LDS views (As/Bs dead after the final barrier)
  u16* qs  = sm;            // [256][32] = 8192 u16
  u16* ks  = sm + 8192;     // [256][32] = 8192 u16
  u16* pm  = sm;            // local P, [4][64][72] = 18432 u16 (alias qs+ks+gap)
  u16* vtL = sm + 18432;    // local [4][28][72] = 8064 u16
  u16* vtG = sm + 16384;    // global, [4] w-stride 2056 = 8224 u16
  u16* p2  = sm + 24608;    // global P, [4][16][32] = 2048 u16

  // ---- C -> LDS in attn layouts; values bit-identical to old qkv
#pragma unroll
  for (int j = 0; j < 6; ++j) {
    const int tile = j * 4 + wave;
    if (tile < 21) {
      const int seg = (tile >= 14) ? 2 : ((tile >= 7) ? 1 : 0);
      const int nn = tile * 16 + c16 - seg * 112;   // 0..111
      const int h = ((nn >= 28) ? 1 : 0) + ((nn >= 56) ? 1 : 0) + ((nn >= 84) ? 1 : 0);
      const int d = nn - h * 28;
#pragma unroll
      for (int st = 0; st < 4; ++st) {
        if (seg == 2) {      // V: 4 consecutive tokens -> one 8B store
          ushort4 o;
          o.x = f2bf(acc[j][st][0]); o.y = f2bf(acc[j][st][1]);
          o.z = f2bf(acc[j][st][2]); o.w = f2bf(acc[j][st][3]);
          if (local)
            *(ushort4*)&vtL[(h * 28 + d) * 72 + st * 16 + g * 4] = o;
          else
            *(ushort4*)&vtG[st * 2056 + (h * 32 + d) * 16 + g * 4] = o;
        } else {
          u16* dst = seg ? ks : qs;
#pragma unroll
          for (int r = 0; r < 4; ++r) {
            const u16 v = f2bf(acc[j][st][r]);
            if (local)
              dst[(h * 64 + st * 16 + g * 4 + r) * 32 + d] = v;
            else
              dst[((st * 4 + h) * 16 + g * 4 + r) * 32 + d] = v;
          }
        }
      }
    }
  }
  // zero K-pads d=28..31 of qs/ks (all 256 rows); global: vtG rows 28..31
  {
    const ushort4 z = {0, 0, 0, 0};
    *(ushort4*)(qs + tid * 32 + 28) = z;
    *(ushort4*)(ks + tid * 32 + 28) = z;
    if (!local) {
      const int w2i = tid >> 6, hq = (tid >> 4) & 3;
      const int dd = 28 + ((tid >> 2) & 3), j4 = tid & 3;
      *(ushort4*)(vtG + w2i * 2056 + (hq * 32 + dd) * 16 + j4 * 4) = z;
    }
  }
  __syncthreads();

  const f4v fz = {0.f, 0.f, 0.f, 0.f};
  if (local) {
    // ================= local attn body (R11) =================
    const int h = wave;
    s8v af2[4], bf2[4];
    for (int t = 0; t < 4; ++t)
      af2[t] = *(const s8v*)&qs[(h * 64 + t * 16 + c16) * 32 + g * 8];
    for (int t = 0; t < 4; ++t)
      bf2[t] = *(const s8v*)&ks[(h * 64 + t * 16 + c16) * 32 + g * 8];
    f4v sc[4][4];
    for (int i = 0; i < 4; ++i)
      for (int j = 0; j < 4; ++j)
        sc[i][j] = MFMA16(af2[i], bf2[j], fz);
    float lrow[4][4];
    const float* ph = pos1 + h * 4096;
    for (int i = 0; i < 4; ++i) {
      for (int r = 0; r < 4; ++r) {
        const int irow = i * 16 + g * 4 + r;
        float mx = -1e30f;
        for (int j = 0; j < 4; ++j) {
          const float v = sc[i][j][r] * SCALE + ph[irow * 64 + j * 16 + c16];
          sc[i][j][r] = v;
          mx = fmaxf(mx, v);
        }
        for (int dd = 1; dd < 16; dd <<= 1) mx = fmaxf(mx, __shfl_xor(mx, dd, 64));
        float sum = 0.f;
        for (int j = 0; j < 4; ++j) {
          const float e = __expf(sc[i][j][r] - mx);
          sc[i][j][r] = e;
          sum += e;
        }
        for (int dd = 1; dd < 16; dd <<= 1) sum += __shfl_xor(sum, dd, 64);
        lrow[i][r] = sum;
      }
    }
    __syncthreads();   // qs/ks frag reads done before pm (aliased) written
    for (int i = 0; i < 4; ++i)
      for (int r = 0; r < 4; ++r) {
        const int irow = i * 16 + g * 4 + r;
        for (int j = 0; j < 4; ++j)
          pm[(h * 64 + irow) * 72 + j * 16 + c16] = f2bf(sc[i][j][r]);
      }
    f4v o[4][2] = {};
    for (int kk = 0; kk < 2; ++kk) {
      s8v ap[4], bv[2];
      for (int t = 0; t < 4; ++t)
        ap[t] = *(const s8v*)&pm[(h * 64 + t * 16 + c16) * 72 + kk * 32 + g * 8];
      for (int t = 0; t < 2; ++t)
        bv[t] = *(const s8v*)&vtL[(h * 28 + t * 16 + c16) * 72 + kk * 32 + g * 8];
      for (int i = 0; i < 4; ++i)
        for (int j = 0; j < 2; ++j)
          o[i][j] = MFMA16(ap[i], bv[j], o[i][j]);
    }
    for (int i = 0; i < 4; ++i)
      for (int r = 0; r < 4; ++r) {
        const int irow = i * 16 + g * 4 + r;
        const int s = base_s + (irow >> 3) * 32 + (irow & 7);
        const float inv = 1.f / lrow[i][r];
        for (int j = 0; j < 2; ++j) {
          const int d = j * 16 + c16;
          if (d < 28)
            attn[(size_t)s * 224 + h * 28 + d] = f2bf(o[i][j][r] * inv);
        }
      }
  } else {
    // ================= global attn body (R11) =================
    const int w = wave;
    const int i = ig * 4 + w;
    const int y = i >> 3, x = i & 7;
    const int w4 = w * 4;
    for (int h = 0; h < 4; ++h) {
      const s8v aq = *(const s8v*)&qs[((w4 + h) * 16 + c16) * 32 + g * 8];
      const s8v bk = *(const s8v*)&ks[((w4 + h) * 16 + c16) * 32 + g * 8];
      const f4v s = MFMA16(aq, bk, fz);
      const float* ph = pos2 + h * 256;
      float l[4];
      for (int r = 0; r < 4; ++r) {
        const float v = s[r] * SCALE + ph[(g * 4 + r) * 16 + c16];
        float mx = v;
        for (int dd = 1; dd < 16; dd <<= 1) mx = fmaxf(mx, __shfl_xor(mx, dd, 64));
        const float e = __expf(v - mx);
        float sum = e;
        for (int dd = 1; dd < 16; dd <<= 1) sum += __shfl_xor(sum, dd, 64);
        l[r] = sum;
        p2[(w * 16 + g * 4 + r) * 32 + c16] = f2bf(e);
        p2[(w * 16 + g * 4 + r) * 32 + c16 + 16] = 0;   // K pad
      }
      const s8v ap = *(const s8v*)&p2[(w * 16 + c16) * 32 + g * 8];  // same-wave RAW
      f4v o[2];
      for (int nt = 0; nt < 2; ++nt) {
        s8v bv = {0, 0, 0, 0, 0, 0, 0, 0};
        if (g < 2)
          bv = *(const s8v*)&vtG[w * 2056 + (h * 32 + nt * 16 + c16) * 16 + g * 8];
        o[nt] = MFMA16(ap, bv, fz);
      }
      for (int nt = 0; nt < 2; ++nt)
        for (int r = 0; r < 4; ++r) {
          const int d = nt * 16 + c16;
          if (d < 28) {
            const int wi = g * 4 + r;
            const int sw = (b * 32 + (wi >> 2) * 8 + y) * 32 + (wi & 3) * 8 + x;
            attn[(size_t)sw * 224 + 112 + h * 28 + d] = f2bf(o[nt][r] / l[r]);
          }
        }
    }
  }
#undef STAGE_A
#undef STAGE_W
}

// ---------------------------------------------------------------------------
// ws layout (bytes):
//   xb    @ 0          : 131072*224*2 = 58,720,256
//   attn  @ 58720256   : 131072*224*2 = 58,720,256
//   w2    @ 117440512  : 2*7*21*512*2 =    301,056   (branch-ordered W frags)
//   woutt @ 117741568  : 256*224*2    =    114,688
// ---------------------------------------------------------------------------
extern "C" void kernel_launch(void* const* d_in, const int* in_sizes, int n_in,
                              void* d_out, int out_size, void* d_ws, size_t ws_size,
                              hipStream_t stream) {
  const float* x    = (const float*)d_in[0];
  const float* Wq   = (const float*)d_in[1];
  const float* Wkv  = (const float*)d_in[2];
  const float* Wout = (const float*)d_in[3];
  const float* bout = (const float*)d_in[4];
  const float* pos1 = (const float*)d_in[5];
  const float* pos2 = (const float*)d_in[6];
  char* ws = (char*)d_ws;
  u16* xb    = (u16*)ws;
  u16* attn  = (u16*)(ws + 58720256);
  u16* w2    = (u16*)(ws + 117440512);
  u16* woutt = (u16*)(ws + 117741568);

  prep_kernel<<<dim3(1024), 256, 0, stream>>>(
      (const float4*)x, Wq, Wkv, Wout, xb, w2, woutt);

  // fused qkv-GEMM + attention; linear W staging from branch-ordered pack
  attn_fused<<<dim3(4096), 256, 53312, stream>>>(xb, w2, pos1, pos2, attn);

  // out = attn @ Wout + bout (f32 out, N=224 -> 2 n-tiles)
  gemm_af<1, 2><<<dim3(1024), 256, 73728, stream>>>(attn, woutt, d_out, bout, 224, 224);
}